// Round 1
// baseline (312.105 us; speedup 1.0000x reference)
//
#include <hip/hip_runtime.h>
#include <math.h>

// ---------------------------------------------------------------------------
// TMCAM: temporal multi-correspondence aggregation, 3-level pyramid.
// Sizes: C=32, T=3, P=3 (p2=9), K=4, DS={3,5,7}, H1=48, H2=24, H3=12.
// One 64-thread wave per (pixel, t) in the agg kernels.
// ---------------------------------------------------------------------------

template<int D>
__global__ __launch_bounds__(64)
void agg_kernel(const float* __restrict__ feats,   // (32, 3, H, W)
                const float* __restrict__ add,     // (3, 32, H, W) or nullptr
                const float* __restrict__ agg_w,   // (4)
                const float* __restrict__ agg_b,   // (1)
                const float* __restrict__ wp_w,    // (288, 64) row-major
                const float* __restrict__ wp_b,    // (288)
                float* __restrict__ out,           // (3, 32, H, W)
                int H, int W)
{
    constexpr int PD = D / 2;
    constexpr int BS = D + 2;          // staged neighborhood edge
    constexpr int NB = BS * BS;
    constexpr int D2 = D * D;
    const int tid = threadIdx.x;
    const int pix = blockIdx.x;
    const int t   = blockIdx.y;
    const int y = pix / W;
    const int x = pix % W;

    __shared__ float sB[NB * 33];      // feat_tm1 staged, [pos*33 + c] (pad 33: no 32-stride conflicts)
    __shared__ float sFt[288];         // feat_t 3x3 unfold, [q*32 + c]
    __shared__ float sPix[64];         // concat(feat_t, feat_tm1) at the pixel
    __shared__ float sProd[288];
    __shared__ int   sIdx[4];
    __shared__ float sInvFt;

    const float* addT = add ? (add + (size_t)t * 32 * H * W) : nullptr;

    // --- stage feat_tm1 = feats[:,t] + add over (D+2)^2 neighborhood (zeros outside) ---
    for (int e = tid; e < NB * 32; e += 64) {
        int pos = e >> 5;
        int c   = e & 31;
        int dy = pos / BS, dx = pos % BS;
        int yy = y - PD - 1 + dy;
        int xx = x - PD - 1 + dx;
        float v = 0.f;
        if (yy >= 0 && yy < H && xx >= 0 && xx < W) {
            v = feats[((c * 3 + t) * H + yy) * W + xx];
            if (addT) v += addT[(c * H + yy) * W + xx];
        }
        sB[pos * 33 + c] = v;
    }
    // --- stage feat_t 3x3 unfold (ft_u), channel index ch = c*9+q, stored [q*32+c] ---
    for (int e = tid; e < 288; e += 64) {
        int q = e >> 5;                // e = q*32 + c
        int c = e & 31;
        int qi = q / 3, qj = q % 3;
        int yy = y + qi - 1, xx = x + qj - 1;
        float v = 0.f;
        if (yy >= 0 && yy < H && xx >= 0 && xx < W) {
            v = feats[((c * 3 + 1) * H + yy) * W + xx];   // center frame = T/2 = 1
            if (addT) v += addT[(c * H + yy) * W + xx];
        }
        sFt[e] = v;
    }
    // --- pixel features for the wm matvec: cat = [feat_t(32), feat_tm1(32)] ---
    {
        int c  = tid & 31;
        int tt = (tid < 32) ? 1 : t;
        float v = feats[((c * 3 + tt) * H + y) * W + x];
        if (addT) v += addT[(c * H + y) * W + x];
        sPix[tid] = v;
    }
    __syncthreads();

    // --- ||ft_u|| over 288 dims (wave reduce) ---
    float p = 0.f;
    for (int e = tid; e < 288; e += 64) p += sFt[e] * sFt[e];
    for (int off = 32; off > 0; off >>= 1) p += __shfl_down(p, off);
    if (tid == 0) sInvFt = 1.f / fmaxf(sqrtf(p), 1e-12f);
    __syncthreads();
    const float invft = sInvFt;

    // --- cosine sim per displacement (lane = dd) ---
    float mySim = -INFINITY;
    if (tid < D2) {
        int di = tid / D, dj = tid % D;
        int Y = y + di - PD, X = x + dj - PD;
        if (Y < 0 || Y >= H || X < 0 || X >= W) {
            mySim = 0.f;               // whole disp column is zero -> dot=0, norm=eps -> sim=0
        } else {
            float dot = 0.f, n2 = 0.f;
            #pragma unroll
            for (int qi = 0; qi < 3; ++qi)
            #pragma unroll
            for (int qj = 0; qj < 3; ++qj) {
                const int base = ((di + qi) * BS + (dj + qj)) * 33;
                const int fb   = (qi * 3 + qj) * 32;
                #pragma unroll
                for (int c = 0; c < 32; ++c) {
                    float bv = sB[base + c];   // conflict-free (pad 33)
                    float fv = sFt[fb + c];    // broadcast
                    dot += fv * bv;
                    n2  += bv * bv;
                }
            }
            mySim = dot * invft / fmaxf(sqrtf(n2), 1e-12f);
        }
    }

    // --- top-4 (descending, ties -> lower index, matching jax.lax.top_k) ---
    for (int k = 0; k < 4; ++k) {
        float v = mySim;
        int  id = tid;
        for (int off = 32; off > 0; off >>= 1) {
            float ov = __shfl_down(v, off);
            int  oid = __shfl_down(id, off);
            if (ov > v || (ov == v && oid < id)) { v = ov; id = oid; }
        }
        int winner = __shfl(id, 0);
        if (tid == 0) sIdx[k] = winner;
        if (tid == winner) mySim = -INFINITY;
    }
    __syncthreads();

    const float aw0 = agg_w[0], aw1 = agg_w[1], aw2 = agg_w[2], aw3 = agg_w[3];
    const float ab  = agg_b[0];
    const int i0 = sIdx[0], i1 = sIdx[1], i2 = sIdx[2], i3 = sIdx[3];

    // --- aggd[o] * wm[o] for o = c*9+q (288 outputs) ---
    const float4* wp4 = (const float4*)wp_w;
    const float4* px4 = (const float4*)sPix;
    for (int o = tid; o < 288; o += 64) {
        int c = o / 9;
        int q = o % 9;
        int qi = q / 3, qj = q % 3;

        float wm = wp_b[o];
        #pragma unroll
        for (int i = 0; i < 16; ++i) {
            float4 wv = wp4[o * 16 + i];
            float4 pv = px4[i];
            wm += wv.x * pv.x + wv.y * pv.y + wv.z * pv.z + wv.w * pv.w;
        }

        float aggd = ab;
        #pragma unroll
        for (int k = 0; k < 4; ++k) {
            int   dd = (k == 0) ? i0 : (k == 1) ? i1 : (k == 2) ? i2 : i3;
            float aw = (k == 0) ? aw0 : (k == 1) ? aw1 : (k == 2) ? aw2 : aw3;
            int di = dd / D, dj = dd % D;
            int Y = y + di - PD, X = x + dj - PD;
            float val = 0.f;
            if (Y >= 0 && Y < H && X >= 0 && X < W)
                val = sB[((di + qi) * BS + (dj + qj)) * 33 + c];
            aggd += aw * val;
        }
        sProd[o] = aggd * wm;
    }
    __syncthreads();

    if (tid < 32) {
        float s = 0.f;
        #pragma unroll
        for (int j = 0; j < 9; ++j) s += sProd[tid * 9 + j];
        out[((t * 32 + tid) * H + y) * W + x] = s;
    }
}

// jax.image.resize(method='linear') 2x: half-pixel centers, edge weights renormalize
// to pure clamp. even o=2m: 0.25*x[m-1]+0.75*x[m] (clamped); odd o=2m+1: 0.75*x[m]+0.25*x[m+1].
__global__ void up2_kernel(const float* __restrict__ in, float* __restrict__ out,
                           int C, int h, int w)
{
    int idx = blockIdx.x * blockDim.x + threadIdx.x;
    int H = 2 * h, W = 2 * w;
    int total = C * H * W;
    if (idx >= total) return;
    int ox = idx % W;
    int oy = (idx / W) % H;
    int c  = idx / (W * H);

    int my = oy >> 1, mx = ox >> 1;
    int y0, y1, x0, x1;
    float wy0, wy1, wx0, wx1;
    if ((oy & 1) == 0) { y0 = max(my - 1, 0); y1 = my; wy0 = 0.25f; wy1 = 0.75f; }
    else               { y0 = my; y1 = min(my + 1, h - 1); wy0 = 0.75f; wy1 = 0.25f; }
    if ((ox & 1) == 0) { x0 = max(mx - 1, 0); x1 = mx; wx0 = 0.25f; wx1 = 0.75f; }
    else               { x0 = mx; x1 = min(mx + 1, w - 1); wx0 = 0.75f; wx1 = 0.25f; }

    const float* pc = in + (size_t)c * h * w;
    float v = wy0 * (wx0 * pc[y0 * w + x0] + wx1 * pc[y0 * w + x1])
            + wy1 * (wx0 * pc[y1 * w + x0] + wx1 * pc[y1 * w + x1]);
    out[idx] = v;
}

// final: out128[o,y,x] = up_b[o] + sum_i up_w[o,i]*a1cat[i,y,x]; then pixel_shuffle r=2.
__global__ void final_kernel(const float* __restrict__ a1,   // (96, 48, 48)
                             const float* __restrict__ up_w, // (128, 96)
                             const float* __restrict__ up_b, // (128)
                             float* __restrict__ out)        // (32, 96, 96)
{
    int idx = blockIdx.x * blockDim.x + threadIdx.x;
    if (idx >= 128 * 48 * 48) return;
    int x = idx % 48;
    int y = (idx / 48) % 48;
    int o = idx / 2304;

    float acc = up_b[o];
    const float* w = up_w + o * 96;
    #pragma unroll 8
    for (int i = 0; i < 96; ++i) acc += w[i] * a1[i * 2304 + y * 48 + x];

    int co = o >> 2, ry = (o >> 1) & 1, rx = o & 1;
    out[((size_t)co * 96 + 2 * y + ry) * 96 + 2 * x + rx] = acc;
}

extern "C" void kernel_launch(void* const* d_in, const int* in_sizes, int n_in,
                              void* d_out, int out_size, void* d_ws, size_t ws_size,
                              hipStream_t stream)
{
    const float* feats_l1 = (const float*)d_in[0];
    const float* feats_l2 = (const float*)d_in[1];
    const float* feats_l3 = (const float*)d_in[2];
    const float* agg_l3_w = (const float*)d_in[3];
    const float* agg_l3_b = (const float*)d_in[4];
    const float* wp_l3_w  = (const float*)d_in[5];
    const float* wp_l3_b  = (const float*)d_in[6];
    const float* agg_l2_w = (const float*)d_in[7];
    const float* agg_l2_b = (const float*)d_in[8];
    const float* wp_l2_w  = (const float*)d_in[9];
    const float* wp_l2_b  = (const float*)d_in[10];
    const float* agg_l1_w = (const float*)d_in[11];
    const float* agg_l1_b = (const float*)d_in[12];
    const float* wp_l1_w  = (const float*)d_in[13];
    const float* wp_l1_b  = (const float*)d_in[14];
    const float* up_w     = (const float*)d_in[15];
    const float* up_b     = (const float*)d_in[16];
    float* out = (float*)d_out;

    float* ws   = (float*)d_ws;
    float* agg3 = ws;                  // 3*32*12*12  = 13824
    float* a3up = agg3 + 13824;        // 3*32*24*24  = 55296
    float* agg2 = a3up + 55296;        // 3*32*24*24  = 55296
    float* a2up = agg2 + 55296;        // 3*32*48*48  = 221184
    float* a1   = a2up + 221184;       // 3*32*48*48  = 221184
                                       // total 566784 floats = 2.27 MB

    // level 3 (12x12, d=3), no add
    agg_kernel<3><<<dim3(12 * 12, 3), 64, 0, stream>>>(
        feats_l3, nullptr, agg_l3_w, agg_l3_b, wp_l3_w, wp_l3_b, agg3, 12, 12);
    up2_kernel<<<(96 * 24 * 24 + 255) / 256, 256, 0, stream>>>(agg3, a3up, 96, 12, 12);

    // level 2 (24x24, d=5), add = up2(a3)
    agg_kernel<5><<<dim3(24 * 24, 3), 64, 0, stream>>>(
        feats_l2, a3up, agg_l2_w, agg_l2_b, wp_l2_w, wp_l2_b, agg2, 24, 24);
    up2_kernel<<<(96 * 48 * 48 + 255) / 256, 256, 0, stream>>>(agg2, a2up, 96, 24, 24);

    // level 1 (48x48, d=7), add = up2(a2), no upsample after
    agg_kernel<7><<<dim3(48 * 48, 3), 64, 0, stream>>>(
        feats_l1, a2up, agg_l1_w, agg_l1_b, wp_l1_w, wp_l1_b, a1, 48, 48);

    // final projection + pixel shuffle
    final_kernel<<<(128 * 48 * 48 + 255) / 256, 256, 0, stream>>>(a1, up_w, up_b, out);
}

// Round 2
// 291.056 us; speedup vs baseline: 1.0723x; 1.0723x over previous
//
#include <hip/hip_runtime.h>
#include <math.h>

// ---------------------------------------------------------------------------
// TMCAM: temporal multi-correspondence aggregation, 3-level pyramid.
// Sizes: C=32, T=3, P=3 (p2=9), K=4, DS={3,5,7}, H1=48, H2=24, H3=12.
// R1: 256-thread blocks (4 waves) per (pixel,t); all phases split across the
// block. Staging loops are pos-major so consecutive lanes hit consecutive x.
// ---------------------------------------------------------------------------

template<int D>
__global__ __launch_bounds__(256)
void agg_kernel(const float* __restrict__ feats,   // (32, 3, H, W)
                const float* __restrict__ add,     // (3, 32, H, W) or nullptr
                const float* __restrict__ agg_w,   // (4)
                const float* __restrict__ agg_b,   // (1)
                const float* __restrict__ wp_w,    // (288, 64) row-major
                const float* __restrict__ wp_b,    // (288)
                float* __restrict__ out,           // (3, 32, H, W)
                int H, int W)
{
    constexpr int PD = D / 2;
    constexpr int BS = D + 2;          // staged neighborhood edge
    constexpr int NB = BS * BS;
    constexpr int D2 = D * D;
    constexpr int PARTS = (D == 7) ? 4 : (D == 5) ? 8 : 16;   // D2*PARTS <= 256
    constexpr int CPER  = 32 / PARTS;  // channels per sim-partial thread

    const int tid = threadIdx.x;
    const int pix = blockIdx.x;
    const int t   = blockIdx.y;
    const int y = pix / W;
    const int x = pix % W;

    __shared__ float sB[NB * 33];      // feat_tm1 staged, [pos*33 + c]
    __shared__ float sFt[288];         // feat_t 3x3 unfold, [q*32 + c]
    __shared__ float sPix[64];         // concat(feat_t, feat_tm1) at the pixel
    __shared__ float sProd[288];
    __shared__ float sDot[256];
    __shared__ float sN2[256];
    __shared__ float sNorm[4];
    __shared__ int   sIdx[4];

    const float* addT = add ? (add + (size_t)t * 32 * H * W) : nullptr;

    // --- stage feat_tm1 = feats[:,t] + add over (D+2)^2 nbhd (zeros outside) ---
    // pos-major: consecutive lanes -> consecutive xx (coalesced-ish rows of BS)
    for (int e = tid; e < NB * 32; e += 256) {
        int pos = e % NB;
        int c   = e / NB;
        int dy = pos / BS, dx = pos % BS;
        int yy = y - PD - 1 + dy;
        int xx = x - PD - 1 + dx;
        float v = 0.f;
        if (yy >= 0 && yy < H && xx >= 0 && xx < W) {
            v = feats[((c * 3 + t) * H + yy) * W + xx];
            if (addT) v += addT[(c * H + yy) * W + xx];
        }
        sB[pos * 33 + c] = v;
    }
    // --- stage feat_t 3x3 unfold; accumulate own ||ft||^2 partial in-register ---
    float normp = 0.f;
    for (int e = tid; e < 288; e += 256) {
        int q = e % 9;                 // pos-major for locality
        int c = e / 9;
        int qi = q / 3, qj = q % 3;
        int yy = y + qi - 1, xx = x + qj - 1;
        float v = 0.f;
        if (yy >= 0 && yy < H && xx >= 0 && xx < W) {
            v = feats[((c * 3 + 1) * H + yy) * W + xx];   // center frame = T/2
            if (addT) v += addT[(c * H + yy) * W + xx];
        }
        sFt[q * 32 + c] = v;
        normp += v * v;
    }
    // --- pixel features for the wm matvec: cat = [feat_t(32), feat_tm1(32)] ---
    if (tid < 64) {
        int c  = tid & 31;
        int tt = (tid < 32) ? 1 : t;
        float v = feats[((c * 3 + tt) * H + y) * W + x];
        if (addT) v += addT[(c * H + y) * W + x];
        sPix[tid] = v;
    }
    // block-reduce the norm partials (wave shfl + one slot per wave)
    for (int off = 32; off > 0; off >>= 1) normp += __shfl_down(normp, off);
    if ((tid & 63) == 0) sNorm[tid >> 6] = normp;
    __syncthreads();

    const float invft = 1.f / fmaxf(sqrtf(sNorm[0] + sNorm[1] + sNorm[2] + sNorm[3]), 1e-12f);

    // --- cosine sim partials: thread = (dd, part), part covers CPER channels ---
    if (tid < D2 * PARTS) {
        const int dd   = tid / PARTS;
        const int part = tid & (PARTS - 1);
        const int di = dd / D, dj = dd % D;
        float dotp = 0.f, n2p = 0.f;
        #pragma unroll
        for (int cc = 0; cc < CPER; ++cc) {
            const int c = part * CPER + cc;
            #pragma unroll
            for (int q = 0; q < 9; ++q) {
                const int qi = q / 3, qj = q % 3;
                float bv = sB[((di + qi) * BS + (dj + qj)) * 33 + c];
                float fv = sFt[q * 32 + c];
                dotp += fv * bv;
                n2p  += bv * bv;
            }
        }
        sDot[tid] = dotp;
        sN2[tid]  = n2p;
    }
    __syncthreads();

    // --- combine + top-4 entirely in wave 0 ---
    if (tid < 64) {
        float mySim = -INFINITY;
        if (tid < D2) {
            int di = tid / D, dj = tid % D;
            int Y = y + di - PD, X = x + dj - PD;
            if (Y < 0 || Y >= H || X < 0 || X >= W) {
                mySim = 0.f;           // zero disp column -> dot=0, norm=eps -> 0
            } else {
                float dot = 0.f, n2 = 0.f;
                #pragma unroll
                for (int p = 0; p < PARTS; ++p) {
                    dot += sDot[tid * PARTS + p];
                    n2  += sN2[tid * PARTS + p];
                }
                mySim = dot * invft / fmaxf(sqrtf(n2), 1e-12f);
            }
        }
        // top-4 descending, ties -> lower index (matches jax.lax.top_k)
        for (int k = 0; k < 4; ++k) {
            float v = mySim;
            int  id = tid;
            for (int off = 32; off > 0; off >>= 1) {
                float ov = __shfl_down(v, off);
                int  oid = __shfl_down(id, off);
                if (ov > v || (ov == v && oid < id)) { v = ov; id = oid; }
            }
            int winner = __shfl(id, 0);
            if (tid == 0) sIdx[k] = winner;
            if (tid == winner) mySim = -INFINITY;
        }
    }
    __syncthreads();

    const float aw0 = agg_w[0], aw1 = agg_w[1], aw2 = agg_w[2], aw3 = agg_w[3];
    const float ab  = agg_b[0];
    const int i0 = sIdx[0], i1 = sIdx[1], i2 = sIdx[2], i3 = sIdx[3];

    // --- aggd[o] * wm[o] for o = c*9+q (288 outputs over 256 threads) ---
    const float4* wp4 = (const float4*)wp_w;
    const float4* px4 = (const float4*)sPix;
    for (int o = tid; o < 288; o += 256) {
        int c = o / 9;
        int q = o % 9;
        int qi = q / 3, qj = q % 3;

        float wm = wp_b[o];
        #pragma unroll
        for (int i = 0; i < 16; ++i) {
            float4 wv = wp4[o * 16 + i];
            float4 pv = px4[i];
            wm += wv.x * pv.x + wv.y * pv.y + wv.z * pv.z + wv.w * pv.w;
        }

        float aggd = ab;
        #pragma unroll
        for (int k = 0; k < 4; ++k) {
            int   dd = (k == 0) ? i0 : (k == 1) ? i1 : (k == 2) ? i2 : i3;
            float aw = (k == 0) ? aw0 : (k == 1) ? aw1 : (k == 2) ? aw2 : aw3;
            int di = dd / D, dj = dd % D;
            int Y = y + di - PD, X = x + dj - PD;
            float val = 0.f;
            if (Y >= 0 && Y < H && X >= 0 && X < W)
                val = sB[((di + qi) * BS + (dj + qj)) * 33 + c];
            aggd += aw * val;
        }
        sProd[o] = aggd * wm;
    }
    __syncthreads();

    if (tid < 32) {
        float s = 0.f;
        #pragma unroll
        for (int j = 0; j < 9; ++j) s += sProd[tid * 9 + j];
        out[((t * 32 + tid) * H + y) * W + x] = s;
    }
}

// jax.image.resize(method='linear') 2x: half-pixel centers, edge weights renorm
// to pure clamp. even o=2m: 0.25*x[m-1]+0.75*x[m]; odd o=2m+1: 0.75*x[m]+0.25*x[m+1].
__global__ void up2_kernel(const float* __restrict__ in, float* __restrict__ out,
                           int C, int h, int w)
{
    int idx = blockIdx.x * blockDim.x + threadIdx.x;
    int H = 2 * h, W = 2 * w;
    int total = C * H * W;
    if (idx >= total) return;
    int ox = idx % W;
    int oy = (idx / W) % H;
    int c  = idx / (W * H);

    int my = oy >> 1, mx = ox >> 1;
    int y0, y1, x0, x1;
    float wy0, wy1, wx0, wx1;
    if ((oy & 1) == 0) { y0 = max(my - 1, 0); y1 = my; wy0 = 0.25f; wy1 = 0.75f; }
    else               { y0 = my; y1 = min(my + 1, h - 1); wy0 = 0.75f; wy1 = 0.25f; }
    if ((ox & 1) == 0) { x0 = max(mx - 1, 0); x1 = mx; wx0 = 0.25f; wx1 = 0.75f; }
    else               { x0 = mx; x1 = min(mx + 1, w - 1); wx0 = 0.75f; wx1 = 0.25f; }

    const float* pc = in + (size_t)c * h * w;
    float v = wy0 * (wx0 * pc[y0 * w + x0] + wx1 * pc[y0 * w + x1])
            + wy1 * (wx0 * pc[y1 * w + x0] + wx1 * pc[y1 * w + x1]);
    out[idx] = v;
}

// final: out128[o,y,x] = up_b[o] + sum_i up_w[o,i]*a1cat[i,y,x]; then pixel_shuffle r=2.
__global__ void final_kernel(const float* __restrict__ a1,   // (96, 48, 48)
                             const float* __restrict__ up_w, // (128, 96)
                             const float* __restrict__ up_b, // (128)
                             float* __restrict__ out)        // (32, 96, 96)
{
    int idx = blockIdx.x * blockDim.x + threadIdx.x;
    if (idx >= 128 * 48 * 48) return;
    int x = idx % 48;
    int y = (idx / 48) % 48;
    int o = idx / 2304;

    float acc = up_b[o];
    const float* w = up_w + o * 96;
    #pragma unroll 8
    for (int i = 0; i < 96; ++i) acc += w[i] * a1[i * 2304 + y * 48 + x];

    int co = o >> 2, ry = (o >> 1) & 1, rx = o & 1;
    out[((size_t)co * 96 + 2 * y + ry) * 96 + 2 * x + rx] = acc;
}

extern "C" void kernel_launch(void* const* d_in, const int* in_sizes, int n_in,
                              void* d_out, int out_size, void* d_ws, size_t ws_size,
                              hipStream_t stream)
{
    const float* feats_l1 = (const float*)d_in[0];
    const float* feats_l2 = (const float*)d_in[1];
    const float* feats_l3 = (const float*)d_in[2];
    const float* agg_l3_w = (const float*)d_in[3];
    const float* agg_l3_b = (const float*)d_in[4];
    const float* wp_l3_w  = (const float*)d_in[5];
    const float* wp_l3_b  = (const float*)d_in[6];
    const float* agg_l2_w = (const float*)d_in[7];
    const float* agg_l2_b = (const float*)d_in[8];
    const float* wp_l2_w  = (const float*)d_in[9];
    const float* wp_l2_b  = (const float*)d_in[10];
    const float* agg_l1_w = (const float*)d_in[11];
    const float* agg_l1_b = (const float*)d_in[12];
    const float* wp_l1_w  = (const float*)d_in[13];
    const float* wp_l1_b  = (const float*)d_in[14];
    const float* up_w     = (const float*)d_in[15];
    const float* up_b     = (const float*)d_in[16];
    float* out = (float*)d_out;

    float* ws   = (float*)d_ws;
    float* agg3 = ws;                  // 3*32*12*12  = 13824
    float* a3up = agg3 + 13824;        // 3*32*24*24  = 55296
    float* agg2 = a3up + 55296;        // 3*32*24*24  = 55296
    float* a2up = agg2 + 55296;        // 3*32*48*48  = 221184
    float* a1   = a2up + 221184;       // 3*32*48*48  = 221184
                                       // total 566784 floats = 2.27 MB

    // level 3 (12x12, d=3), no add
    agg_kernel<3><<<dim3(12 * 12, 3), 256, 0, stream>>>(
        feats_l3, nullptr, agg_l3_w, agg_l3_b, wp_l3_w, wp_l3_b, agg3, 12, 12);
    up2_kernel<<<(96 * 24 * 24 + 255) / 256, 256, 0, stream>>>(agg3, a3up, 96, 12, 12);

    // level 2 (24x24, d=5), add = up2(a3)
    agg_kernel<5><<<dim3(24 * 24, 3), 256, 0, stream>>>(
        feats_l2, a3up, agg_l2_w, agg_l2_b, wp_l2_w, wp_l2_b, agg2, 24, 24);
    up2_kernel<<<(96 * 48 * 48 + 255) / 256, 256, 0, stream>>>(agg2, a2up, 96, 24, 24);

    // level 1 (48x48, d=7), add = up2(a2), no upsample after
    agg_kernel<7><<<dim3(48 * 48, 3), 256, 0, stream>>>(
        feats_l1, a2up, agg_l1_w, agg_l1_b, wp_l1_w, wp_l1_b, a1, 48, 48);

    // final projection + pixel shuffle
    final_kernel<<<(128 * 48 * 48 + 255) / 256, 256, 0, stream>>>(a1, up_w, up_b, out);
}